// Round 12
// baseline (609.589 us; speedup 1.0000x reference)
//
#include <hip/hip_runtime.h>
#include <stdint.h>

// ---------------------------------------------------------------------------
// TransformerBlock: B=32, L=512, D=256, H=4.
// Inputs fp32 (dict order); OUTPUT fp32.
// r19: flash paired q-tiles — each block processes {qt, 7-qt} sequentially:
//   grid 1024 variable-work blocks (1..8 units) -> 512 constant-work blocks
//   (9 units): one perfectly balanced round on 512 slots, zero straggler
//   tail. XCD affinity preserved (all pair-blocks of a bh share L&7).
//   Per-pass body = proven r14 body; one barrier guards p=1 K staging
//   against p=0's final V reads. Traffic/regs/LDS unchanged.
// r18: FFN2+LN2 fused via gemm_ln (neutral, kept: fewer dispatches).
// r16: gemm_bt swizzle + dbuf stage-ahead; Wo -> AttO -> ln1_kernel.
// r15: prep_all/tv fusions.
// ws = 59 + 5*CB MiB + CB*32KB (CB=32 -> single chunk at ws=256MiB).
// ---------------------------------------------------------------------------
#define SEQ   512
#define DM    256
#define NB    32
#define NH    4
#define HD    (NH * DM)           // 1024
#define PE_MASK (SEQ * DM - 1)    // 131071
#define NEGV  (-4294967295.0f)

typedef __attribute__((ext_vector_type(8))) short short8;   // 8 x bf16
typedef __attribute__((ext_vector_type(4))) float f32x4;    // MFMA accumulator

#if defined(__has_builtin)
#if __has_builtin(__builtin_amdgcn_global_load_lds)
#define HAS_ASYNC 1
#endif
#endif
#ifndef HAS_ASYNC
#define HAS_ASYNC 0
#endif

__device__ __forceinline__ float b2f(unsigned short u) {
    return __uint_as_float(((uint32_t)u) << 16);
}
__device__ __forceinline__ unsigned short f2b(float f) {
    uint32_t u = __float_as_uint(f);
    u += 0x7fffu + ((u >> 16) & 1u);   // RNE
    return (unsigned short)(u >> 16);
}
// raw v_exp_f32: 2^x on the transcendental pipe (input pre-scaled by log2e)
__device__ __forceinline__ float fast_exp2(float x) {
    float r;
    asm("v_exp_f32 %0, %1" : "=v"(r) : "v"(x));
    return r;
}

// LDS bank swizzle: involution XORing byte bits [6:4] with bits [9:7].
__device__ __forceinline__ int swzb(int b) {
    return b ^ (((b >> 7) & 7) << 4);
}

// ---------------------------------------------------------------------------
// prep_all: fused preprocessing, one dispatch (13504 blocks):
//   [0,64) mask | [64,832) WqWkWv^T | [832,1088) Wo^T | [1088,1216) w1,w2
//   [1216,13504) Q/K/V + pe -> bf16
// ---------------------------------------------------------------------------
__global__ __launch_bounds__(256) void prep_all(
    const unsigned char* __restrict__ mask_raw, int* __restrict__ maskc,
    const float* __restrict__ Wq, const float* __restrict__ Wk,
    const float* __restrict__ Wv, unsigned short* __restrict__ WqT,
    const float* __restrict__ Wo, unsigned short* __restrict__ WoT,
    const float* __restrict__ w1, const float* __restrict__ w2,
    unsigned short* __restrict__ o1, unsigned short* __restrict__ o2,
    const float* __restrict__ Q, const float* __restrict__ K,
    const float* __restrict__ V, const float* __restrict__ pe,
    unsigned short* __restrict__ Qp, unsigned short* __restrict__ Kp,
    unsigned short* __restrict__ Vp)
{
    __shared__ unsigned short tile[32][33];
    __shared__ int enc[2];
    const int blk = blockIdx.x;
    const int tid = threadIdx.x;

    if (blk < 64) {
        if (tid == 0) { enc[0] = 0; enc[1] = 0; }
        __syncthreads();
        if (tid < 255 && mask_raw[tid * 4 + 1]) atomicOr(&enc[0], 1);
        if (tid < 128 && ((const int*)mask_raw)[tid * 2 + 1]) atomicOr(&enc[1], 1);
        __syncthreads();
        int i = blk * 256 + tid;
        int v;
        if (enc[0])      v = (mask_raw[i] != 0);
        else if (enc[1]) v = (((const int*)mask_raw)[i] != 0);
        else             v = ((((const int*)mask_raw)[i * 2] |
                              ((const int*)mask_raw)[i * 2 + 1]) != 0);
        maskc[i] = v;
    } else if (blk < 832) {
        int t = blk - 64;
        int x = t & 31, y = (t >> 5) & 7, zz = t >> 8;
        const float* in = (zz == 0) ? Wq : (zz == 1) ? Wk : Wv;
        unsigned short* op = WqT + (long)zz * 262144;
        int r0 = y * 32, c0 = x * 32;
        int i = tid >> 3, j = (tid & 7) * 4;
        float4 v = *reinterpret_cast<const float4*>(in + (long)(r0 + i) * HD + c0 + j);
        tile[i][j + 0] = f2b(v.x); tile[i][j + 1] = f2b(v.y);
        tile[i][j + 2] = f2b(v.z); tile[i][j + 3] = f2b(v.w);
        __syncthreads();
        ushort4 w;
        w.x = tile[j + 0][i]; w.y = tile[j + 1][i];
        w.z = tile[j + 2][i]; w.w = tile[j + 3][i];
        *reinterpret_cast<ushort4*>(op + (long)(c0 + i) * DM + r0 + j) = w;
    } else if (blk < 1088) {
        int t = blk - 832;
        int x = t & 7, y = t >> 3;
        int r0 = y * 32, c0 = x * 32;
        int i = tid >> 3, j = (tid & 7) * 4;
        float4 v = *reinterpret_cast<const float4*>(Wo + (long)(r0 + i) * DM + c0 + j);
        tile[i][j + 0] = f2b(v.x); tile[i][j + 1] = f2b(v.y);
        tile[i][j + 2] = f2b(v.z); tile[i][j + 3] = f2b(v.w);
        __syncthreads();
        ushort4 w;
        w.x = tile[j + 0][i]; w.y = tile[j + 1][i];
        w.z = tile[j + 2][i]; w.w = tile[j + 3][i];
        *reinterpret_cast<ushort4*>(WoT + (long)(c0 + i) * HD + r0 + j) = w;
    } else if (blk < 1216) {
        int t = blk - 1088;
        const float* in = (t < 64) ? w1 : w2;
        unsigned short* out = (t < 64) ? o1 : o2;
        long i = (long)((t & 63) * 256 + tid) * 4;
        float4 x = *reinterpret_cast<const float4*>(in + i);
        ushort4 o;
        o.x = f2b(x.x); o.y = f2b(x.y); o.z = f2b(x.z); o.w = f2b(x.w);
        *reinterpret_cast<ushort4*>(out + i) = o;
    } else {
        int t = blk - 1216;
        int seg = t >> 12;
        const float* X = (seg == 0) ? Q : (seg == 1) ? K : V;
        unsigned short* O = (seg == 0) ? Qp : (seg == 1) ? Kp : Vp;
        long i = (long)((t & 4095) * 256 + tid) * 4;
        float4 x = *reinterpret_cast<const float4*>(X + i);
        float4 p = *reinterpret_cast<const float4*>(pe + (i & PE_MASK));
        ushort4 o;
        o.x = f2b(x.x + p.x); o.y = f2b(x.y + p.y);
        o.z = f2b(x.z + p.z); o.w = f2b(x.w + p.w);
        *reinterpret_cast<ushort4*>(O + i) = o;
    }
}

// ---------------------------------------------------------------------------
// tv_kernel: fused per-head V transpose + vmean partial sums (both read Vh).
// ---------------------------------------------------------------------------
__global__ __launch_bounds__(256) void tv_kernel(
    const unsigned short* __restrict__ Vh, unsigned short* __restrict__ VhT,
    float* __restrict__ part, int nbl)
{
    __shared__ unsigned short tile[32][33];
    const int blk = blockIdx.x;
    const int tid = threadIdx.x;
    const int nT = nbl * NH * 128;           // 8x16 tiles per (bl,h)

    if (blk < nT) {
        int x = blk & 7, y = (blk >> 3) & 15, zz = blk >> 7;
        int b = zz / NH, hh = zz % NH;
        const unsigned short* ip = Vh + (long)b * SEQ * HD + (long)hh * DM;
        unsigned short* op = VhT + (long)b * SEQ * HD + (long)hh * SEQ * DM;
        int r0 = y * 32, c0 = x * 32;
        int i = tid >> 3, j = (tid & 7) * 4;
        ushort4 v = *reinterpret_cast<const ushort4*>(ip + (long)(r0 + i) * HD + c0 + j);
        tile[i][j + 0] = v.x; tile[i][j + 1] = v.y;
        tile[i][j + 2] = v.z; tile[i][j + 3] = v.w;
        __syncthreads();
        ushort4 w;
        w.x = tile[j + 0][i]; w.y = tile[j + 1][i];
        w.z = tile[j + 2][i]; w.w = tile[j + 3][i];
        *reinterpret_cast<ushort4*>(op + (long)(c0 + i) * SEQ + r0 + j) = w;
    } else {
        int t = blk - nT;
        int bl = t >> 3, seg = t & 7;
        const unsigned short* p = Vh + (long)bl * SEQ * HD + (long)seg * 64 * HD;
        int c = tid * 4;
        float s0 = 0.f, s1 = 0.f, s2 = 0.f, s3 = 0.f;
        for (int l = 0; l < 64; ++l) {
            ushort4 v = *reinterpret_cast<const ushort4*>(p + (long)l * HD + c);
            s0 += b2f(v.x); s1 += b2f(v.y); s2 += b2f(v.z); s3 += b2f(v.w);
        }
        float4 o = {s0, s1, s2, s3};
        *reinterpret_cast<float4*>(part + (long)(bl * 8 + seg) * HD + c) = o;
    }
}

// ---------------------------------------------------------------------------
// Pure-bf16 MFMA GEMM: C = scl*A.Bt (+bias, relu), 128x128 tile.
// Swizzled As/Bs + dbuf stage-ahead (r16). `scale` applies to z==0 only.
// ---------------------------------------------------------------------------
template<bool BIAS, bool RELU, bool OUTBF16>
__global__ __launch_bounds__(256) void gemm_bt(
    const unsigned short* __restrict__ A, int lda,
    const unsigned short* __restrict__ B, int ldb,
    void* __restrict__ Cv, int ldc,
    const float* __restrict__ bias, float scale, int K, int Hdiv,
    long sAb, long sAh, long sAz,
    long sBb, long sBh, long sBz,
    long sCb, long sCh, long sCz)
{
    const int m0 = blockIdx.y * 128;
    const int n0 = blockIdx.x * 128;
    int z  = blockIdx.z;
    int bb = z / Hdiv, hh = z % Hdiv;
    const unsigned short* Ab = A + bb * sAb + hh * sAh + (long)z * sAz;
    const unsigned short* Bb = B + bb * sBb + hh * sBh + (long)z * sBz;
    long coff = bb * sCb + hh * sCh + (long)z * sCz;
    const float scl = (z == 0) ? scale : 1.0f;

    __shared__ unsigned short As[2][128 * 32];
    __shared__ unsigned short Bs[2][128 * 32];

    const int tid  = threadIdx.x;
    const int lane = tid & 63;
    const int wave = tid >> 6;
    const int wm   = (wave >> 1) * 64;
    const int wn   = (wave & 1) * 64;
    const int lm   = lane & 15;
    const int kq   = (lane >> 4) * 8;

    f32x4 acc[4][4] = {};

    auto stage = [&](int b, int k0) {
#pragma unroll
        for (int it = 0; it < 2; ++it) {
            int id = tid + it * 256;
#if HAS_ASYNC
            int U  = swzb(id * 16);
            int r  = U >> 6;
            int c8 = ((U >> 4) & 3) * 8;
            const unsigned short* gA = Ab + (long)(m0 + r) * lda + k0 + c8;
            const unsigned short* gB = Bb + (long)(n0 + r) * ldb + k0 + c8;
            unsigned short* lA = &As[b][(size_t)(it * 256 + wave * 64) * 8];
            unsigned short* lB = &Bs[b][(size_t)(it * 256 + wave * 64) * 8];
            __builtin_amdgcn_global_load_lds(
                (const __attribute__((address_space(1))) void*)gA,
                (__attribute__((address_space(3))) void*)lA, 16, 0, 0);
            __builtin_amdgcn_global_load_lds(
                (const __attribute__((address_space(1))) void*)gB,
                (__attribute__((address_space(3))) void*)lB, 16, 0, 0);
#else
            int r  = id >> 2;
            int c8 = (id & 3) * 8;
            const unsigned short* gA = Ab + (long)(m0 + r) * lda + k0 + c8;
            const unsigned short* gB = Bb + (long)(n0 + r) * ldb + k0 + c8;
            *reinterpret_cast<uint4*>((char*)As[b] + swzb(id * 16)) =
                *reinterpret_cast<const uint4*>(gA);
            *reinterpret_cast<uint4*>((char*)Bs[b] + swzb(id * 16)) =
                *reinterpret_cast<const uint4*>(gB);
#endif
        }
    };

    stage(0, 0);
    __syncthreads();
    const int nk = K >> 5;
    for (int kk = 0; kk < nk; ++kk) {
        const int cur = kk & 1;
        if (kk + 1 < nk)
            stage(cur ^ 1, (kk + 1) * 32);

        short8 af[4], bfr[4];
#pragma unroll
        for (int i = 0; i < 4; ++i)
            af[i] = *reinterpret_cast<const short8*>(
                (const char*)As[cur] + swzb((wm + i * 16 + lm) * 64 + kq * 2));
#pragma unroll
        for (int j = 0; j < 4; ++j)
            bfr[j] = *reinterpret_cast<const short8*>(
                (const char*)Bs[cur] + swzb((wn + j * 16 + lm) * 64 + kq * 2));
#pragma unroll
        for (int i = 0; i < 4; ++i)
#pragma unroll
            for (int j = 0; j < 4; ++j)
                acc[i][j] = __builtin_amdgcn_mfma_f32_16x16x32_bf16(af[i], bfr[j], acc[i][j], 0, 0, 0);
        __syncthreads();
    }

#pragma unroll
    for (int j = 0; j < 4; ++j) {
        int col  = n0 + wn + j * 16 + lm;
        float bv = 0.f;
        if (BIAS) bv = bias[col];
#pragma unroll
        for (int i = 0; i < 4; ++i) {
#pragma unroll
            for (int r = 0; r < 4; ++r) {
                int row = m0 + wm + i * 16 + (lane >> 4) * 4 + r;
                float v = acc[i][j][r] * scl + bv;
                if (RELU) v = fmaxf(v, 0.f);
                long idx = coff + (long)row * ldc + col;
                if (OUTBF16) reinterpret_cast<unsigned short*>(Cv)[idx] = f2b(v);
                else         reinterpret_cast<float*>(Cv)[idx] = v;
            }
        }
    }
}

// ---------------------------------------------------------------------------
// gemm_ln: C = A.Bt (+bias) then row LayerNorm fused in the epilogue.
// Used ONLY for FFN2+LN2 (K=256): out = LN((H1@w2^T + b2) + Xf).
// ---------------------------------------------------------------------------
template<bool ADDPE, bool BIAS, bool OUTB16>
__global__ __launch_bounds__(256) void gemm_ln(
    const unsigned short* __restrict__ A, int lda,
    const unsigned short* __restrict__ B, int ldb,
    const float* __restrict__ bias,
    const float* __restrict__ Rf, const float* __restrict__ pe,
    const float* __restrict__ gamma, const float* __restrict__ beta,
    float* __restrict__ outf, unsigned short* __restrict__ outb,
    int K, long row0)
{
    const int m0 = blockIdx.x * 64;

    __shared__ __align__(16) float Xt[64][260];   // 66.6 KiB; staging overlays
    unsigned short* Sh = reinterpret_cast<unsigned short*>(&Xt[0][0]);
    unsigned short* AsP[2] = { Sh, Sh + 2048 };
    unsigned short* BsP[2] = { Sh + 4096, Sh + 4096 + 8192 };

    const int tid  = threadIdx.x;
    const int lane = tid & 63;
    const int wave = tid >> 6;
    const int wm   = (wave >> 1) * 32;     // 2 wave-rows of 32
    const int wn   = (wave & 1) * 128;     // 2 wave-cols of 128
    const int lm   = lane & 15;
    const int qg   = lane >> 4;
    const int kq   = qg * 8;

    f32x4 acc[2][8] = {};

    auto stage = [&](int b, int k0) {
        {
            int id = tid;
#if HAS_ASYNC
            int U  = swzb(id * 16);
            int r  = U >> 6;
            int c8 = ((U >> 4) & 3) * 8;
            const unsigned short* gA = A + (long)(m0 + r) * lda + k0 + c8;
            unsigned short* lA = AsP[b] + (size_t)(wave * 64) * 8;
            __builtin_amdgcn_global_load_lds(
                (const __attribute__((address_space(1))) void*)gA,
                (__attribute__((address_space(3))) void*)lA, 16, 0, 0);
#else
            int r  = id >> 2;
            int c8 = (id & 3) * 8;
            const unsigned short* gA = A + (long)(m0 + r) * lda + k0 + c8;
            *reinterpret_cast<uint4*>((char*)AsP[b] + swzb(id * 16)) =
                *reinterpret_cast<const uint4*>(gA);
#endif
        }
#pragma unroll
        for (int it = 0; it < 4; ++it) {
            int id = tid + it * 256;
#if HAS_ASYNC
            int U  = swzb(id * 16);
            int r  = U >> 6;
            int c8 = ((U >> 4) & 3) * 8;
            const unsigned short* gB = B + (long)r * ldb + k0 + c8;
            unsigned short* lB = BsP[b] + (size_t)(it * 256 + wave * 64) * 8;
            __builtin_amdgcn_global_load_lds(
                (const __attribute__((address_space(1))) void*)gB,
                (__attribute__((address_space(3))) void*)lB, 16, 0, 0);
#else
            int r  = id >> 2;
            int c8 = (id & 3) * 8;
            const unsigned short* gB = B + (long)r * ldb + k0 + c8;
            *reinterpret_cast<uint4*>((char*)BsP[b] + swzb(id * 16)) =
                *reinterpret_cast<const uint4*>(gB);
#endif
        }
    };

    stage(0, 0);
    __syncthreads();
    const int nk = K >> 5;
    for (int kk = 0; kk < nk; ++kk) {
        const int cur = kk & 1;
        if (kk + 1 < nk)
            stage(cur ^ 1, (kk + 1) * 32);

        short8 af[2], bfr[8];
#pragma unroll
        for (int i = 0; i < 2; ++i)
            af[i] = *reinterpret_cast<const short8*>(
                (const char*)AsP[cur] + swzb((wm + i * 16 + lm) * 64 + kq * 2));
#pragma unroll
        for (int j = 0; j < 8; ++j)
            bfr[j] = *reinterpret_cast<const short8*>(
                (const char*)BsP[cur] + swzb((wn + j * 16 + lm) * 64 + kq * 2));
#pragma unroll
        for (int i = 0; i < 2; ++i)
#pragma unroll
            for (int j = 0; j < 8; ++j)
                acc[i][j] = __builtin_amdgcn_mfma_f32_16x16x32_bf16(af[i], bfr[j], acc[i][j], 0, 0, 0);
        __syncthreads();
    }

    // ---- epilogue step 1: acc -> LDS fp32 tile ----
#pragma unroll
    for (int j = 0; j < 8; ++j) {
        int col = wn + j * 16 + lm;
#pragma unroll
        for (int i = 0; i < 2; ++i)
#pragma unroll
            for (int r = 0; r < 4; ++r)
                Xt[wm + i * 16 + qg * 4 + r][col] = acc[i][j][r];
    }
    __syncthreads();

    // ---- epilogue step 2: per-row LN (4 rows per pass, 16 passes) ----
    for (int rr = 0; rr < 16; ++rr) {
        int lrow = rr * 4 + (tid >> 6);
        long grow = row0 + m0 + lrow;
        long base = grow * DM + lane * 4;
        int d0 = lane * 4;
        float4 xv = *reinterpret_cast<const float4*>(&Xt[lrow][d0]);
        float x[4] = {xv.x, xv.y, xv.z, xv.w};
        if (BIAS) {
            float4 bv = *reinterpret_cast<const float4*>(bias + d0);
            x[0] += bv.x; x[1] += bv.y; x[2] += bv.z; x[3] += bv.w;
        }
        float4 rv = *reinterpret_cast<const float4*>(Rf + base);
        x[0] += rv.x; x[1] += rv.y; x[2] += rv.z; x[3] += rv.w;
        if (ADDPE) {
            float4 pv = *reinterpret_cast<const float4*>(pe + (base & PE_MASK));
            x[0] += pv.x; x[1] += pv.y; x[2] += pv.z; x[3] += pv.w;
        }
        float s = x[0] + x[1] + x[2] + x[3];
#pragma unroll
        for (int off = 32; off > 0; off >>= 1) s += __shfl_xor(s, off);
        float mu = s * (1.0f / DM);
        float vs = 0.f;
#pragma unroll
        for (int t = 0; t < 4; ++t) { float d = x[t] - mu; vs += d * d; }
#pragma unroll
        for (int off = 32; off > 0; off >>= 1) vs += __shfl_xor(vs, off);
        float inv = rsqrtf(vs * (1.0f / DM) + 1e-5f);
        float4 g  = *reinterpret_cast<const float4*>(gamma + d0);
        float4 bt = *reinterpret_cast<const float4*>(beta + d0);
        float4 o;
        o.x = (x[0] - mu) * inv * g.x + bt.x;
        o.y = (x[1] - mu) * inv * g.y + bt.y;
        o.z = (x[2] - mu) * inv * g.z + bt.z;
        o.w = (x[3] - mu) * inv * g.w + bt.w;
        *reinterpret_cast<float4*>(outf + base) = o;
        if (OUTB16) {
            ushort4 ob;
            ob.x = f2b(o.x); ob.y = f2b(o.y); ob.z = f2b(o.z); ob.w = f2b(o.w);
            *reinterpret_cast<ushort4*>(outb + base) = ob;
        }
    }
}

// ---------------------------------------------------------------------------
// flash_attn staging (rule 21: linear LDS dest + pre-swizzled global src).
// ---------------------------------------------------------------------------
__device__ __forceinline__ void stage_k32(
    unsigned short* __restrict__ buf, const unsigned short* __restrict__ Ak,
    int kc, int qt, int tid, int wave)
{
    for (int it = 0; it <= qt; ++it) {
        int id = tid + it * 256;
#if HAS_ASYNC
        int U = swzb(id * 16);
        const unsigned short* g = Ak + (long)(U >> 6) * HD + kc * 32 + ((U >> 4) & 3) * 8;
        unsigned short* l = buf + (size_t)(it * 256 + wave * 64) * 8;
        __builtin_amdgcn_global_load_lds(
            (const __attribute__((address_space(1))) void*)g,
            (__attribute__((address_space(3))) void*)l, 16, 0, 0);
#else
        const unsigned short* g = Ak + (long)(id >> 2) * HD + kc * 32 + (id & 3) * 8;
        *reinterpret_cast<uint4*>((char*)buf + swzb(id * 16)) =
            *reinterpret_cast<const uint4*>(g);
#endif
    }
}

__device__ __forceinline__ void stage_v64(
    unsigned short* __restrict__ buf, const unsigned short* __restrict__ Av,
    int c64, int tid, int wave)
{
#pragma unroll
    for (int it = 0; it < 8; ++it) {
        int id = tid + it * 256;
#if HAS_ASYNC
        int U = swzb(id * 16);
        const unsigned short* g = Av + (long)(U >> 7) * SEQ + c64 * 64 + ((U >> 4) & 7) * 8;
        unsigned short* l = buf + (size_t)(it * 256 + wave * 64) * 8;
        __builtin_amdgcn_global_load_lds(
            (const __attribute__((address_space(1))) void*)g,
            (__attribute__((address_space(3))) void*)l, 16, 0, 0);
#else
        const unsigned short* g = Av + (long)(id >> 3) * SEQ + c64 * 64 + (id & 7) * 8;
        *reinterpret_cast<uint4*>((char*)buf + swzb(id * 16)) =
            *reinterpret_cast<const uint4*>(g);
#endif
    }
}

// ---------------------------------------------------------------------------
// Fused flash attention, paired q-tiles (r19). Grid 4*nbh blocks; each block
// processes q-tiles {pi, 7-pi} of one (b,h) sequentially -> constant 9 work
// units/block, one perfectly balanced round on 512 slots, zero tail.
// XCD = L&7 (all pair-blocks of a bh share it). Per-pass body = r14 proven:
// causal dbuf stage-ahead phase 1, in-register softmax (Q pre-scaled by
// scale*log2e -> v_exp_f32, deferred norm, early bf16 P-pack), causal
// 64-key V-tile phase 2, masked rows <- V column mean from `part`.
// ---------------------------------------------------------------------------
__global__ __launch_bounds__(256, 2) void flash_attn(
    const unsigned short* __restrict__ Qh,
    const unsigned short* __restrict__ Kh,
    const unsigned short* __restrict__ VhT,
    const float* __restrict__ part,
    unsigned short* __restrict__ Vatt,
    const int* __restrict__ maskc, int bh0, int nbh)
{
    const int tid  = threadIdx.x;
    const int lane = tid & 63;
    const int wave = tid >> 6;
    const int lm   = lane & 15;
    const int qg   = lane >> 4;
    const int kq   = qg * 8;

    const int L = blockIdx.x;
    int z, pi;
    if ((nbh & 7) == 0) {
        int x = L & 7, m = L >> 3;
        pi = m & 3;                    // pair index 0..3 -> {pi, 7-pi}
        z  = x + 8 * (m >> 2);
    } else {
        z = L % nbh; pi = L / nbh;
    }
    const int b_l = z >> 2, h = z & 3;
    const long qkbase = (long)b_l * SEQ * HD + (long)h * DM;
    const unsigned short* Aq = Qh + qkbase;
    const unsigned short* Ak = Kh + qkbase;
    const unsigned short* Av = VhT + (long)b_l * SEQ * HD + (long)h * SEQ * DM;
    unsigned short* Ov = Vatt + qkbase;
    const int bglob = (bh0 + z) >> 2;

    __shared__ unsigned short Ks[2 * SEQ * 32];             // 64 KiB dbuf
    __shared__ __align__(16) unsigned short Pw[4][16][40];  // 5 KiB

    for (int p = 0; p < 2; ++p) {
        const int qt  = p ? (7 - pi) : pi;
        const int m0  = qt * 64;
        const int wq0 = m0 + wave * 16;
        const int NT  = (m0 >> 4) + wave + 1;   // causal tile bound

        if (p) __syncthreads();   // guard K staging vs pass-0's final V reads

        f32x4 S[32] = {};

        // ---- Phase 1: S = Q.K^T over 8 d-chunks, causal dbuf stage-ahead --
        stage_k32(Ks, Ak, 0, qt, tid, wave);
        __syncthreads();
        for (int kc = 0; kc < 8; ++kc) {
            unsigned short* cur = (kc & 1) ? (Ks + SEQ * 32) : Ks;
            unsigned short* nxt = (kc & 1) ? Ks : (Ks + SEQ * 32);
            short8 qf = *reinterpret_cast<const short8*>(
                Aq + (long)(wq0 + lm) * HD + kc * 32 + kq);
            if (kc < 7) {
                stage_k32(nxt, Ak, kc + 1, qt, tid, wave);
            } else {
                stage_v64(Ks, Av, 0, tid, wave);   // V tile 0 prefetch
            }
            __builtin_amdgcn_s_setprio(1);
#pragma unroll
            for (int nt = 0; nt < 32; ++nt) {
                if (nt < NT) {
                    int row = nt * 16 + lm;
                    short8 bf = *reinterpret_cast<const short8*>(
                        (const char*)cur + swzb(row * 64 + qg * 16));
                    S[nt] = __builtin_amdgcn_mfma_f32_16x16x32_bf16(qf, bf, S[nt], 0, 0, 0);
                }
            }
            __builtin_amdgcn_s_setprio(0);
            __syncthreads();
        }

        // ---- Softmax (S pre-scaled by scale*log2e at the Q projection) ----
        int   qrow[4];
        bool  rowm[4];
        float mx[4], sm[4];
#pragma unroll
        for (int r = 0; r < 4; ++r) {
            int q = wq0 + qg * 4 + r;
            qrow[r] = q;
            rowm[r] = maskc[bglob * SEQ + q] != 0;
            mx[r] = -3.4e38f;
        }
#pragma unroll
        for (int nt = 0; nt < 32; ++nt) {
            int k = nt * 16 + lm;
#pragma unroll
            for (int r = 0; r < 4; ++r) {
                float v = S[nt][r];
                if (k > qrow[r]) v = NEGV;
                S[nt][r] = v;
                mx[r] = fmaxf(mx[r], v);
            }
        }
#pragma unroll
        for (int r = 0; r < 4; ++r) {
#pragma unroll
            for (int off = 8; off >= 1; off >>= 1)
                mx[r] = fmaxf(mx[r], __shfl_xor(mx[r], off));
            sm[r] = 0.f;
        }
        uint32_t pk[32][2];
#pragma unroll
        for (int nt = 0; nt < 32; ++nt) {
            float e0 = fast_exp2(S[nt][0] - mx[0]);
            float e1 = fast_exp2(S[nt][1] - mx[1]);
            float e2 = fast_exp2(S[nt][2] - mx[2]);
            float e3 = fast_exp2(S[nt][3] - mx[3]);
            sm[0] += e0; sm[1] += e1; sm[2] += e2; sm[3] += e3;
            pk[nt][0] = (uint32_t)f2b(e0) | ((uint32_t)f2b(e1) << 16);
            pk[nt][1] = (uint32_t)f2b(e2) | ((uint32_t)f2b(e3) << 16);
        }
#pragma unroll
        for (int r = 0; r < 4; ++r) {
#pragma unroll
            for (int off = 8; off >= 1; off >>= 1)
                sm[r] += __shfl_xor(sm[r], off);
            sm[r] = 1.0f / sm[r];
        }

        // ---- Phase 2: O = P.V, causal NC tiles of 64 keys, V dbuf ----
        unsigned short* Vb0 = Ks;
        unsigned short* Vb1 = Ks + 16384;
        const int NC = qt + 1;
        f32x4 O[16] = {};
#pragma unroll
        for (int c64 = 0; c64 < 8; ++c64) {
            if (c64 < NC) {
                unsigned short* Vcur = (c64 & 1) ? Vb1 : Vb0;
                __syncthreads();
                if (c64 + 1 < NC) {
                    unsigned short* Vnext = (c64 & 1) ? Vb0 : Vb1;
                    stage_v64(Vnext, Av, c64 + 1, tid, wave);
                }
#pragma unroll
                for (int t = 0; t < 2; ++t) {
#pragma unroll
                    for (int tt = 0; tt < 2; ++tt) {
                        int nt = c64 * 4 + t * 2 + tt;
#pragma unroll
                        for (int r = 0; r < 4; ++r)
                            Pw[wave][qg * 4 + r][tt * 16 + lm] =
                                (unsigned short)(pk[nt][r >> 1] >> ((r & 1) * 16));
                    }
                    short8 pf = *reinterpret_cast<const short8*>(&Pw[wave][lm][kq]);
                    __builtin_amdgcn_s_setprio(1);
#pragma unroll
                    for (int nt2 = 0; nt2 < 16; ++nt2) {
                        int row = nt2 * 16 + lm;
                        short8 vf = *reinterpret_cast<const short8*>(
                            (const char*)Vcur + swzb(row * 128 + t * 64 + qg * 16));
                        O[nt2] = __builtin_amdgcn_mfma_f32_16x16x32_bf16(pf, vf, O[nt2], 0, 0, 0);
                    }
                    __builtin_amdgcn_s_setprio(0);
                }
            }
        }

        // ---- epilogue: masked rows <- V column mean; live rows <- O/sum ----
        const float* pb = part + (long)(b_l * 8) * HD + h * DM + lm;
        float vmf[16];
#pragma unroll
        for (int nt2 = 0; nt2 < 16; ++nt2) {
            float s = 0.f;
#pragma unroll
            for (int seg = 0; seg < 8; ++seg)
                s += pb[(long)seg * HD + nt2 * 16];
            vmf[nt2] = s * (1.0f / SEQ);
        }
#pragma unroll
        for (int nt2 = 0; nt2 < 16; ++nt2) {
#pragma unroll
            for (int r = 0; r < 4; ++r) {
                int l = wq0 + qg * 4 + r;
                float val = rowm[r] ? vmf[nt2] : O[nt2][r] * sm[r];
                Ov[(long)l * HD + nt2 * 16 + lm] = f2b(val);
            }
        }
    }
}

// ---------------------------------------------------------------------------
// LN1: x = bf16 AttO + fp32 Q + fp32 pe  ->  fp32 Xf AND bf16 Xb
// ---------------------------------------------------------------------------
__global__ __launch_bounds__(256) void ln1_kernel(
    const unsigned short* __restrict__ AttO, const float* __restrict__ Q,
    const float* __restrict__ pe,
    const float* __restrict__ gamma, const float* __restrict__ beta,
    float* __restrict__ outf, unsigned short* __restrict__ outb)
{
    int row  = blockIdx.x * 4 + (threadIdx.x >> 6);
    int lane = threadIdx.x & 63;
    long base = (long)row * DM + lane * 4;
    ushort4 a = *reinterpret_cast<const ushort4*>(AttO + base);
    float4 qv = *reinterpret_cast<const float4*>(Q + base);
    float4 pv = *reinterpret_cast<const float4*>(pe + (base & PE_MASK));
    float x[4] = {b2f(a.x) + qv.x + pv.x, b2f(a.y) + qv.y + pv.y,
                  b2f(a.z) + qv.z + pv.z, b2f(a.w) + qv.w + pv.w};
    float s = x[0] + x[1] + x[2] + x[3];
#pragma unroll
    for (int off = 32; off > 0; off >>= 1) s += __shfl_xor(s, off);
    float mu = s * (1.0f / DM);
    float vs = 0.f;
#pragma unroll
    for (int t = 0; t < 4; ++t) { float d = x[t] - mu; vs += d * d; }
#pragma unroll
    for (int off = 32; off > 0; off >>= 1) vs += __shfl_xor(vs, off);
    float inv = rsqrtf(vs * (1.0f / DM) + 1e-5f);
    int d0 = lane * 4;
    float4 g = *reinterpret_cast<const float4*>(gamma + d0);
    float4 bt = *reinterpret_cast<const float4*>(beta + d0);
    float4 o;
    o.x = (x[0] - mu) * inv * g.x + bt.x;
    o.y = (x[1] - mu) * inv * g.y + bt.y;
    o.z = (x[2] - mu) * inv * g.z + bt.z;
    o.w = (x[3] - mu) * inv * g.w + bt.w;
    *reinterpret_cast<float4*>(outf + base) = o;
    ushort4 ob;
    ob.x = f2b(o.x); ob.y = f2b(o.y); ob.z = f2b(o.z); ob.w = f2b(o.w);
    *reinterpret_cast<ushort4*>(outb + base) = ob;
}

// ---------------------------------------------------------------------------
extern "C" void kernel_launch(void* const* d_in, const int* in_sizes, int n_in,
                              void* d_out, int out_size, void* d_ws, size_t ws_size,
                              hipStream_t stream)
{
    const float* Q  = (const float*)d_in[0];
    const float* Ki = (const float*)d_in[1];
    const float* Vi = (const float*)d_in[2];
    const unsigned char* mask_raw = (const unsigned char*)d_in[3];
    const float* pe = (const float*)d_in[4];
    const float* Wq = (const float*)d_in[5];
    const float* Wk = (const float*)d_in[6];
    const float* Wv = (const float*)d_in[7];
    const float* Wo = (const float*)d_in[8];
    const float* w1 = (const float*)d_in[9];
    const float* b1 = (const float*)d_in[10];
    const float* w2 = (const float*)d_in[11];
    const float* b2 = (const float*)d_in[12];
    const float* gamma = (const float*)d_in[13];
    const float* beta  = (const float*)d_in[14];
    float* out = (float*)d_out;

    const size_t MiB = 1048576;
    char* ws = (char*)d_ws;

    // ---- adaptive chunk size: footprint = 59 + max(5*CB + 32KB*CB, 24) MiB --
    int CB = 1;
    for (int cb = 32; cb >= 1; cb >>= 1) {
        size_t scr_sz = (size_t)(5 * cb) * MiB + (size_t)cb * 32768;
        if (scr_sz < 24 * MiB) scr_sz = 24 * MiB;
        if ((59 * MiB + scr_sz) <= ws_size) { CB = cb; break; }
    }
    const int NCH = NB / CB;

    // ---- fixed low regions ----
    unsigned short* WqT  = (unsigned short*)(ws);                 // 512 KiB each
    unsigned short* WkT  = WqT + 262144;
    unsigned short* WvT  = WkT + 262144;
    unsigned short* WoT  = WvT + 262144;
    unsigned short* w1b  = (unsigned short*)(ws + 2 * MiB);       // 128 KiB
    unsigned short* w2b  = w1b + 65536;                           // 128 KiB
    int*            maskc = (int*)(ws + 2 * MiB + 262144);        // 64 KiB
    unsigned short* Qp   = (unsigned short*)(ws + 3 * MiB);       // 8 MiB bf16
    unsigned short* Kp   = (unsigned short*)(ws + 11 * MiB);      // 8 MiB
    unsigned short* Vp   = (unsigned short*)(ws + 19 * MiB);      // 8 MiB
    unsigned short* AttO = (unsigned short*)(ws + 27 * MiB);      // 8 MiB
    unsigned short* Xb   = (unsigned short*)(ws + 35 * MiB);      // 8 MiB
    float*          Xf   = (float*)(ws + 43 * MiB);               // 16 MiB
    char*           scr  = ws + 59 * MiB;
    // chunk scratch (CB MiB each)
    unsigned short* Qh   = (unsigned short*)(scr);
    unsigned short* Kh   = (unsigned short*)(scr + (size_t)CB * MiB);
    unsigned short* Vh   = (unsigned short*)(scr + (size_t)2 * CB * MiB);
    unsigned short* VhT  = (unsigned short*)(scr + (size_t)3 * CB * MiB);
    unsigned short* Vatt = (unsigned short*)(scr + (size_t)4 * CB * MiB);
    // vmean partial sums (per chunk; dead at tail-alias time)
    float*          part = (float*)(scr + (size_t)5 * CB * MiB);  // CB*32 KiB
    // tail aliases over scratch (chunk buffers dead by then)
    unsigned short* H1   = (unsigned short*)(scr);                // 8 MiB bf16

    // softmax scale * log2(e), folded into the Q projection (z==0 slab)
    const float SCALE_Q = (float)((1.0 / (16.0 + 1e-6)) * 1.4426950408889634);
    const long CROWS = (long)CB * SEQ;
    const long CBELT = (long)CB * MiB / 2;     // chunk-buffer stride, elements

    // 0. fused prep (1 dispatch)
    prep_all<<<13504, 256, 0, stream>>>(
        mask_raw, maskc, Wq, Wk, Wv, WqT, Wo, WoT,
        w1, w2, w1b, w2b, Q, Ki, Vi, pe, Qp, Kp, Vp);

    // 1. attention in NCH chunks of CB batches
    for (int c = 0; c < NCH; ++c) {
        const long r0   = (long)c * CROWS;
        const int  bh0  = c * CB * NH;
        const int  gy   = (int)(CROWS / 128);
        const int  nbh  = CB * NH;

        // all 3 projections in ONE dispatch (z=0: Q scaled by SCALE_Q, 1:K, 2:V)
        gemm_bt<false, false, true><<<dim3(8, gy, 3), 256, 0, stream>>>(
            Qp + r0 * DM, DM, WqT, DM, Qh, HD, nullptr, SCALE_Q, DM,
            1, 4194304, 0, 0, 262144, 0, 0, CBELT, 0, 0);

        // fused per-head V transpose + vmean partial sums (1 dispatch)
        tv_kernel<<<CB * NH * 128 + CB * 8, 256, 0, stream>>>(
            Vh, VhT, part, CB);

        // fused attention, paired q-tiles (1 dispatch, 4*nbh blocks)
        flash_attn<<<dim3(4 * nbh, 1, 1), 256, 0, stream>>>(
            Qh, Kh, VhT, part, Vatt, maskc, bh0, nbh);

        // output projection for this chunk -> AttO rows [r0, r0+CROWS)
        gemm_bt<false, false, true><<<dim3(2, gy, 1), 256, 0, stream>>>(
            Vatt, HD, WoT, HD, AttO + r0 * DM, DM, nullptr, 1.f, HD,
            1, 0,0,0, 0,0,0, 0,0,0);
    }

    // 2. LN1: X = LN(Q + pe + AttO) -> fp32 Xf + bf16 Xb
    ln1_kernel<<<4096, 256, 0, stream>>>(AttO, Q, pe, gamma, beta, Xf, Xb);

    // 3. FFN1: H1 = relu(Xb @ w1^T + b1) -> bf16
    gemm_bt<true, true, true><<<dim3(2, 128, 1), 256, 0, stream>>>(
        Xb, DM, w1b, DM, H1, DM, b1, 1.f, DM, 1, 0,0,0, 0,0,0, 0,0,0);

    // 4. FFN2 + LN2 fused: out = LN((H1@w2^T + b2) + Xf)
    gemm_ln<false, true, false><<<256, 256, 0, stream>>>(
        H1, DM, w2b, DM, b2, Xf, nullptr, gamma, beta,
        out, nullptr, DM, 0);
}

// Round 13
// 324.079 us; speedup vs baseline: 1.8810x; 1.8810x over previous
//
#include <hip/hip_runtime.h>
#include <stdint.h>

// ---------------------------------------------------------------------------
// TransformerBlock: B=32, L=512, D=256, H=4.
// Inputs fp32 (dict order); OUTPUT fp32.
// r20 = r18 REVERT (r19's paired q-tiles unrolled the pass loop -> S/pk/O
// live-range duplication -> ~250MB scratch spill, flash 76->350us. Reverted.)
// r18: r16 base + FFN2+LN2 fusion via gemm_ln (neutral perf, one fewer
//   dispatch; kept). gemm_ln<false,true,false>: 64x256 tile + LN epilogue;
//   out = LN((H1@w2^T + b2) + Xf). Bit-identical math to split kernels.
// r16: gemm_bt swizzle + dbuf stage-ahead; Wo -> AttO -> ln1_kernel.
// r15: prep_all/tv fusions. flash = r14 (proven: XCD swizzle + complementary
//   qt pairing across blocks, LDS XOR-swizzle, causal dbuf stage-ahead,
//   scale*log2e folded into Q projection -> v_exp_f32, 64-key V tiles,
//   setprio, deferred norm, early bf16 P-pack, launch_bounds(256,2)).
// ws = 59 + 5*CB MiB + CB*32KB (CB=32 -> single chunk at ws=256MiB).
// ---------------------------------------------------------------------------
#define SEQ   512
#define DM    256
#define NB    32
#define NH    4
#define HD    (NH * DM)           // 1024
#define PE_MASK (SEQ * DM - 1)    // 131071
#define NEGV  (-4294967295.0f)

typedef __attribute__((ext_vector_type(8))) short short8;   // 8 x bf16
typedef __attribute__((ext_vector_type(4))) float f32x4;    // MFMA accumulator

#if defined(__has_builtin)
#if __has_builtin(__builtin_amdgcn_global_load_lds)
#define HAS_ASYNC 1
#endif
#endif
#ifndef HAS_ASYNC
#define HAS_ASYNC 0
#endif

__device__ __forceinline__ float b2f(unsigned short u) {
    return __uint_as_float(((uint32_t)u) << 16);
}
__device__ __forceinline__ unsigned short f2b(float f) {
    uint32_t u = __float_as_uint(f);
    u += 0x7fffu + ((u >> 16) & 1u);   // RNE
    return (unsigned short)(u >> 16);
}
// raw v_exp_f32: 2^x on the transcendental pipe (input pre-scaled by log2e)
__device__ __forceinline__ float fast_exp2(float x) {
    float r;
    asm("v_exp_f32 %0, %1" : "=v"(r) : "v"(x));
    return r;
}

// LDS bank swizzle: involution XORing byte bits [6:4] with bits [9:7].
__device__ __forceinline__ int swzb(int b) {
    return b ^ (((b >> 7) & 7) << 4);
}

// ---------------------------------------------------------------------------
// prep_all: fused preprocessing, one dispatch (13504 blocks):
//   [0,64) mask | [64,832) WqWkWv^T | [832,1088) Wo^T | [1088,1216) w1,w2
//   [1216,13504) Q/K/V + pe -> bf16
// ---------------------------------------------------------------------------
__global__ __launch_bounds__(256) void prep_all(
    const unsigned char* __restrict__ mask_raw, int* __restrict__ maskc,
    const float* __restrict__ Wq, const float* __restrict__ Wk,
    const float* __restrict__ Wv, unsigned short* __restrict__ WqT,
    const float* __restrict__ Wo, unsigned short* __restrict__ WoT,
    const float* __restrict__ w1, const float* __restrict__ w2,
    unsigned short* __restrict__ o1, unsigned short* __restrict__ o2,
    const float* __restrict__ Q, const float* __restrict__ K,
    const float* __restrict__ V, const float* __restrict__ pe,
    unsigned short* __restrict__ Qp, unsigned short* __restrict__ Kp,
    unsigned short* __restrict__ Vp)
{
    __shared__ unsigned short tile[32][33];
    __shared__ int enc[2];
    const int blk = blockIdx.x;
    const int tid = threadIdx.x;

    if (blk < 64) {
        if (tid == 0) { enc[0] = 0; enc[1] = 0; }
        __syncthreads();
        if (tid < 255 && mask_raw[tid * 4 + 1]) atomicOr(&enc[0], 1);
        if (tid < 128 && ((const int*)mask_raw)[tid * 2 + 1]) atomicOr(&enc[1], 1);
        __syncthreads();
        int i = blk * 256 + tid;
        int v;
        if (enc[0])      v = (mask_raw[i] != 0);
        else if (enc[1]) v = (((const int*)mask_raw)[i] != 0);
        else             v = ((((const int*)mask_raw)[i * 2] |
                              ((const int*)mask_raw)[i * 2 + 1]) != 0);
        maskc[i] = v;
    } else if (blk < 832) {
        int t = blk - 64;
        int x = t & 31, y = (t >> 5) & 7, zz = t >> 8;
        const float* in = (zz == 0) ? Wq : (zz == 1) ? Wk : Wv;
        unsigned short* op = WqT + (long)zz * 262144;
        int r0 = y * 32, c0 = x * 32;
        int i = tid >> 3, j = (tid & 7) * 4;
        float4 v = *reinterpret_cast<const float4*>(in + (long)(r0 + i) * HD + c0 + j);
        tile[i][j + 0] = f2b(v.x); tile[i][j + 1] = f2b(v.y);
        tile[i][j + 2] = f2b(v.z); tile[i][j + 3] = f2b(v.w);
        __syncthreads();
        ushort4 w;
        w.x = tile[j + 0][i]; w.y = tile[j + 1][i];
        w.z = tile[j + 2][i]; w.w = tile[j + 3][i];
        *reinterpret_cast<ushort4*>(op + (long)(c0 + i) * DM + r0 + j) = w;
    } else if (blk < 1088) {
        int t = blk - 832;
        int x = t & 7, y = t >> 3;
        int r0 = y * 32, c0 = x * 32;
        int i = tid >> 3, j = (tid & 7) * 4;
        float4 v = *reinterpret_cast<const float4*>(Wo + (long)(r0 + i) * DM + c0 + j);
        tile[i][j + 0] = f2b(v.x); tile[i][j + 1] = f2b(v.y);
        tile[i][j + 2] = f2b(v.z); tile[i][j + 3] = f2b(v.w);
        __syncthreads();
        ushort4 w;
        w.x = tile[j + 0][i]; w.y = tile[j + 1][i];
        w.z = tile[j + 2][i]; w.w = tile[j + 3][i];
        *reinterpret_cast<ushort4*>(WoT + (long)(c0 + i) * HD + r0 + j) = w;
    } else if (blk < 1216) {
        int t = blk - 1088;
        const float* in = (t < 64) ? w1 : w2;
        unsigned short* out = (t < 64) ? o1 : o2;
        long i = (long)((t & 63) * 256 + tid) * 4;
        float4 x = *reinterpret_cast<const float4*>(in + i);
        ushort4 o;
        o.x = f2b(x.x); o.y = f2b(x.y); o.z = f2b(x.z); o.w = f2b(x.w);
        *reinterpret_cast<ushort4*>(out + i) = o;
    } else {
        int t = blk - 1216;
        int seg = t >> 12;
        const float* X = (seg == 0) ? Q : (seg == 1) ? K : V;
        unsigned short* O = (seg == 0) ? Qp : (seg == 1) ? Kp : Vp;
        long i = (long)((t & 4095) * 256 + tid) * 4;
        float4 x = *reinterpret_cast<const float4*>(X + i);
        float4 p = *reinterpret_cast<const float4*>(pe + (i & PE_MASK));
        ushort4 o;
        o.x = f2b(x.x + p.x); o.y = f2b(x.y + p.y);
        o.z = f2b(x.z + p.z); o.w = f2b(x.w + p.w);
        *reinterpret_cast<ushort4*>(O + i) = o;
    }
}

// ---------------------------------------------------------------------------
// tv_kernel: fused per-head V transpose + vmean partial sums (both read Vh).
// ---------------------------------------------------------------------------
__global__ __launch_bounds__(256) void tv_kernel(
    const unsigned short* __restrict__ Vh, unsigned short* __restrict__ VhT,
    float* __restrict__ part, int nbl)
{
    __shared__ unsigned short tile[32][33];
    const int blk = blockIdx.x;
    const int tid = threadIdx.x;
    const int nT = nbl * NH * 128;           // 8x16 tiles per (bl,h)

    if (blk < nT) {
        int x = blk & 7, y = (blk >> 3) & 15, zz = blk >> 7;
        int b = zz / NH, hh = zz % NH;
        const unsigned short* ip = Vh + (long)b * SEQ * HD + (long)hh * DM;
        unsigned short* op = VhT + (long)b * SEQ * HD + (long)hh * SEQ * DM;
        int r0 = y * 32, c0 = x * 32;
        int i = tid >> 3, j = (tid & 7) * 4;
        ushort4 v = *reinterpret_cast<const ushort4*>(ip + (long)(r0 + i) * HD + c0 + j);
        tile[i][j + 0] = v.x; tile[i][j + 1] = v.y;
        tile[i][j + 2] = v.z; tile[i][j + 3] = v.w;
        __syncthreads();
        ushort4 w;
        w.x = tile[j + 0][i]; w.y = tile[j + 1][i];
        w.z = tile[j + 2][i]; w.w = tile[j + 3][i];
        *reinterpret_cast<ushort4*>(op + (long)(c0 + i) * SEQ + r0 + j) = w;
    } else {
        int t = blk - nT;
        int bl = t >> 3, seg = t & 7;
        const unsigned short* p = Vh + (long)bl * SEQ * HD + (long)seg * 64 * HD;
        int c = tid * 4;
        float s0 = 0.f, s1 = 0.f, s2 = 0.f, s3 = 0.f;
        for (int l = 0; l < 64; ++l) {
            ushort4 v = *reinterpret_cast<const ushort4*>(p + (long)l * HD + c);
            s0 += b2f(v.x); s1 += b2f(v.y); s2 += b2f(v.z); s3 += b2f(v.w);
        }
        float4 o = {s0, s1, s2, s3};
        *reinterpret_cast<float4*>(part + (long)(bl * 8 + seg) * HD + c) = o;
    }
}

// ---------------------------------------------------------------------------
// Pure-bf16 MFMA GEMM: C = scl*A.Bt (+bias, relu), 128x128 tile.
// Swizzled As/Bs + dbuf stage-ahead (r16). `scale` applies to z==0 only.
// ---------------------------------------------------------------------------
template<bool BIAS, bool RELU, bool OUTBF16>
__global__ __launch_bounds__(256) void gemm_bt(
    const unsigned short* __restrict__ A, int lda,
    const unsigned short* __restrict__ B, int ldb,
    void* __restrict__ Cv, int ldc,
    const float* __restrict__ bias, float scale, int K, int Hdiv,
    long sAb, long sAh, long sAz,
    long sBb, long sBh, long sBz,
    long sCb, long sCh, long sCz)
{
    const int m0 = blockIdx.y * 128;
    const int n0 = blockIdx.x * 128;
    int z  = blockIdx.z;
    int bb = z / Hdiv, hh = z % Hdiv;
    const unsigned short* Ab = A + bb * sAb + hh * sAh + (long)z * sAz;
    const unsigned short* Bb = B + bb * sBb + hh * sBh + (long)z * sBz;
    long coff = bb * sCb + hh * sCh + (long)z * sCz;
    const float scl = (z == 0) ? scale : 1.0f;

    __shared__ unsigned short As[2][128 * 32];
    __shared__ unsigned short Bs[2][128 * 32];

    const int tid  = threadIdx.x;
    const int lane = tid & 63;
    const int wave = tid >> 6;
    const int wm   = (wave >> 1) * 64;
    const int wn   = (wave & 1) * 64;
    const int lm   = lane & 15;
    const int kq   = (lane >> 4) * 8;

    f32x4 acc[4][4] = {};

    auto stage = [&](int b, int k0) {
#pragma unroll
        for (int it = 0; it < 2; ++it) {
            int id = tid + it * 256;
#if HAS_ASYNC
            int U  = swzb(id * 16);
            int r  = U >> 6;
            int c8 = ((U >> 4) & 3) * 8;
            const unsigned short* gA = Ab + (long)(m0 + r) * lda + k0 + c8;
            const unsigned short* gB = Bb + (long)(n0 + r) * ldb + k0 + c8;
            unsigned short* lA = &As[b][(size_t)(it * 256 + wave * 64) * 8];
            unsigned short* lB = &Bs[b][(size_t)(it * 256 + wave * 64) * 8];
            __builtin_amdgcn_global_load_lds(
                (const __attribute__((address_space(1))) void*)gA,
                (__attribute__((address_space(3))) void*)lA, 16, 0, 0);
            __builtin_amdgcn_global_load_lds(
                (const __attribute__((address_space(1))) void*)gB,
                (__attribute__((address_space(3))) void*)lB, 16, 0, 0);
#else
            int r  = id >> 2;
            int c8 = (id & 3) * 8;
            const unsigned short* gA = Ab + (long)(m0 + r) * lda + k0 + c8;
            const unsigned short* gB = Bb + (long)(n0 + r) * ldb + k0 + c8;
            *reinterpret_cast<uint4*>((char*)As[b] + swzb(id * 16)) =
                *reinterpret_cast<const uint4*>(gA);
            *reinterpret_cast<uint4*>((char*)Bs[b] + swzb(id * 16)) =
                *reinterpret_cast<const uint4*>(gB);
#endif
        }
    };

    stage(0, 0);
    __syncthreads();
    const int nk = K >> 5;
    for (int kk = 0; kk < nk; ++kk) {
        const int cur = kk & 1;
        if (kk + 1 < nk)
            stage(cur ^ 1, (kk + 1) * 32);

        short8 af[4], bfr[4];
#pragma unroll
        for (int i = 0; i < 4; ++i)
            af[i] = *reinterpret_cast<const short8*>(
                (const char*)As[cur] + swzb((wm + i * 16 + lm) * 64 + kq * 2));
#pragma unroll
        for (int j = 0; j < 4; ++j)
            bfr[j] = *reinterpret_cast<const short8*>(
                (const char*)Bs[cur] + swzb((wn + j * 16 + lm) * 64 + kq * 2));
#pragma unroll
        for (int i = 0; i < 4; ++i)
#pragma unroll
            for (int j = 0; j < 4; ++j)
                acc[i][j] = __builtin_amdgcn_mfma_f32_16x16x32_bf16(af[i], bfr[j], acc[i][j], 0, 0, 0);
        __syncthreads();
    }

#pragma unroll
    for (int j = 0; j < 4; ++j) {
        int col  = n0 + wn + j * 16 + lm;
        float bv = 0.f;
        if (BIAS) bv = bias[col];
#pragma unroll
        for (int i = 0; i < 4; ++i) {
#pragma unroll
            for (int r = 0; r < 4; ++r) {
                int row = m0 + wm + i * 16 + (lane >> 4) * 4 + r;
                float v = acc[i][j][r] * scl + bv;
                if (RELU) v = fmaxf(v, 0.f);
                long idx = coff + (long)row * ldc + col;
                if (OUTBF16) reinterpret_cast<unsigned short*>(Cv)[idx] = f2b(v);
                else         reinterpret_cast<float*>(Cv)[idx] = v;
            }
        }
    }
}

// ---------------------------------------------------------------------------
// gemm_ln: C = A.Bt (+bias) then row LayerNorm fused in the epilogue.
// Used ONLY for FFN2+LN2 (K=256): out = LN((H1@w2^T + b2) + Xf).
// Tile 64 rows x 256 cols (full D) so each block owns complete rows.
// Epilogue: acc -> LDS fp32 [64][260] (2-way banks = free) -> barrier ->
// ln2-style per-4-row LN pass. Add order (acc+b2)+Xf == old bit-exact path.
// ---------------------------------------------------------------------------
template<bool ADDPE, bool BIAS, bool OUTB16>
__global__ __launch_bounds__(256) void gemm_ln(
    const unsigned short* __restrict__ A, int lda,
    const unsigned short* __restrict__ B, int ldb,
    const float* __restrict__ bias,
    const float* __restrict__ Rf, const float* __restrict__ pe,
    const float* __restrict__ gamma, const float* __restrict__ beta,
    float* __restrict__ outf, unsigned short* __restrict__ outb,
    int K, long row0)
{
    const int m0 = blockIdx.x * 64;

    __shared__ __align__(16) float Xt[64][260];   // 66.6 KiB; staging overlays
    unsigned short* Sh = reinterpret_cast<unsigned short*>(&Xt[0][0]);
    unsigned short* AsP[2] = { Sh, Sh + 2048 };
    unsigned short* BsP[2] = { Sh + 4096, Sh + 4096 + 8192 };

    const int tid  = threadIdx.x;
    const int lane = tid & 63;
    const int wave = tid >> 6;
    const int wm   = (wave >> 1) * 32;     // 2 wave-rows of 32
    const int wn   = (wave & 1) * 128;     // 2 wave-cols of 128
    const int lm   = lane & 15;
    const int qg   = lane >> 4;
    const int kq   = qg * 8;

    f32x4 acc[2][8] = {};

    auto stage = [&](int b, int k0) {
        {
            int id = tid;
#if HAS_ASYNC
            int U  = swzb(id * 16);
            int r  = U >> 6;
            int c8 = ((U >> 4) & 3) * 8;
            const unsigned short* gA = A + (long)(m0 + r) * lda + k0 + c8;
            unsigned short* lA = AsP[b] + (size_t)(wave * 64) * 8;
            __builtin_amdgcn_global_load_lds(
                (const __attribute__((address_space(1))) void*)gA,
                (__attribute__((address_space(3))) void*)lA, 16, 0, 0);
#else
            int r  = id >> 2;
            int c8 = (id & 3) * 8;
            const unsigned short* gA = A + (long)(m0 + r) * lda + k0 + c8;
            *reinterpret_cast<uint4*>((char*)AsP[b] + swzb(id * 16)) =
                *reinterpret_cast<const uint4*>(gA);
#endif
        }
#pragma unroll
        for (int it = 0; it < 4; ++it) {
            int id = tid + it * 256;
#if HAS_ASYNC
            int U  = swzb(id * 16);
            int r  = U >> 6;
            int c8 = ((U >> 4) & 3) * 8;
            const unsigned short* gB = B + (long)r * ldb + k0 + c8;
            unsigned short* lB = BsP[b] + (size_t)(it * 256 + wave * 64) * 8;
            __builtin_amdgcn_global_load_lds(
                (const __attribute__((address_space(1))) void*)gB,
                (__attribute__((address_space(3))) void*)lB, 16, 0, 0);
#else
            int r  = id >> 2;
            int c8 = (id & 3) * 8;
            const unsigned short* gB = B + (long)r * ldb + k0 + c8;
            *reinterpret_cast<uint4*>((char*)BsP[b] + swzb(id * 16)) =
                *reinterpret_cast<const uint4*>(gB);
#endif
        }
    };

    stage(0, 0);
    __syncthreads();
    const int nk = K >> 5;
    for (int kk = 0; kk < nk; ++kk) {
        const int cur = kk & 1;
        if (kk + 1 < nk)
            stage(cur ^ 1, (kk + 1) * 32);

        short8 af[2], bfr[8];
#pragma unroll
        for (int i = 0; i < 2; ++i)
            af[i] = *reinterpret_cast<const short8*>(
                (const char*)AsP[cur] + swzb((wm + i * 16 + lm) * 64 + kq * 2));
#pragma unroll
        for (int j = 0; j < 8; ++j)
            bfr[j] = *reinterpret_cast<const short8*>(
                (const char*)BsP[cur] + swzb((wn + j * 16 + lm) * 64 + kq * 2));
#pragma unroll
        for (int i = 0; i < 2; ++i)
#pragma unroll
            for (int j = 0; j < 8; ++j)
                acc[i][j] = __builtin_amdgcn_mfma_f32_16x16x32_bf16(af[i], bfr[j], acc[i][j], 0, 0, 0);
        __syncthreads();
    }

    // ---- epilogue step 1: acc -> LDS fp32 tile ----
#pragma unroll
    for (int j = 0; j < 8; ++j) {
        int col = wn + j * 16 + lm;
#pragma unroll
        for (int i = 0; i < 2; ++i)
#pragma unroll
            for (int r = 0; r < 4; ++r)
                Xt[wm + i * 16 + qg * 4 + r][col] = acc[i][j][r];
    }
    __syncthreads();

    // ---- epilogue step 2: per-row LN (4 rows per pass, 16 passes) ----
    for (int rr = 0; rr < 16; ++rr) {
        int lrow = rr * 4 + (tid >> 6);
        long grow = row0 + m0 + lrow;
        long base = grow * DM + lane * 4;
        int d0 = lane * 4;
        float4 xv = *reinterpret_cast<const float4*>(&Xt[lrow][d0]);
        float x[4] = {xv.x, xv.y, xv.z, xv.w};
        if (BIAS) {
            float4 bv = *reinterpret_cast<const float4*>(bias + d0);
            x[0] += bv.x; x[1] += bv.y; x[2] += bv.z; x[3] += bv.w;
        }
        float4 rv = *reinterpret_cast<const float4*>(Rf + base);
        x[0] += rv.x; x[1] += rv.y; x[2] += rv.z; x[3] += rv.w;
        if (ADDPE) {
            float4 pv = *reinterpret_cast<const float4*>(pe + (base & PE_MASK));
            x[0] += pv.x; x[1] += pv.y; x[2] += pv.z; x[3] += pv.w;
        }
        float s = x[0] + x[1] + x[2] + x[3];
#pragma unroll
        for (int off = 32; off > 0; off >>= 1) s += __shfl_xor(s, off);
        float mu = s * (1.0f / DM);
        float vs = 0.f;
#pragma unroll
        for (int t = 0; t < 4; ++t) { float d = x[t] - mu; vs += d * d; }
#pragma unroll
        for (int off = 32; off > 0; off >>= 1) vs += __shfl_xor(vs, off);
        float inv = rsqrtf(vs * (1.0f / DM) + 1e-5f);
        float4 g  = *reinterpret_cast<const float4*>(gamma + d0);
        float4 bt = *reinterpret_cast<const float4*>(beta + d0);
        float4 o;
        o.x = (x[0] - mu) * inv * g.x + bt.x;
        o.y = (x[1] - mu) * inv * g.y + bt.y;
        o.z = (x[2] - mu) * inv * g.z + bt.z;
        o.w = (x[3] - mu) * inv * g.w + bt.w;
        *reinterpret_cast<float4*>(outf + base) = o;
        if (OUTB16) {
            ushort4 ob;
            ob.x = f2b(o.x); ob.y = f2b(o.y); ob.z = f2b(o.z); ob.w = f2b(o.w);
            *reinterpret_cast<ushort4*>(outb + base) = ob;
        }
    }
}

// ---------------------------------------------------------------------------
// flash_attn staging (rule 21: linear LDS dest + pre-swizzled global src).
// ---------------------------------------------------------------------------
__device__ __forceinline__ void stage_k32(
    unsigned short* __restrict__ buf, const unsigned short* __restrict__ Ak,
    int kc, int qt, int tid, int wave)
{
    for (int it = 0; it <= qt; ++it) {
        int id = tid + it * 256;
#if HAS_ASYNC
        int U = swzb(id * 16);
        const unsigned short* g = Ak + (long)(U >> 6) * HD + kc * 32 + ((U >> 4) & 3) * 8;
        unsigned short* l = buf + (size_t)(it * 256 + wave * 64) * 8;
        __builtin_amdgcn_global_load_lds(
            (const __attribute__((address_space(1))) void*)g,
            (__attribute__((address_space(3))) void*)l, 16, 0, 0);
#else
        const unsigned short* g = Ak + (long)(id >> 2) * HD + kc * 32 + (id & 3) * 8;
        *reinterpret_cast<uint4*>((char*)buf + swzb(id * 16)) =
            *reinterpret_cast<const uint4*>(g);
#endif
    }
}

__device__ __forceinline__ void stage_v64(
    unsigned short* __restrict__ buf, const unsigned short* __restrict__ Av,
    int c64, int tid, int wave)
{
#pragma unroll
    for (int it = 0; it < 8; ++it) {
        int id = tid + it * 256;
#if HAS_ASYNC
        int U = swzb(id * 16);
        const unsigned short* g = Av + (long)(U >> 7) * SEQ + c64 * 64 + ((U >> 4) & 7) * 8;
        unsigned short* l = buf + (size_t)(it * 256 + wave * 64) * 8;
        __builtin_amdgcn_global_load_lds(
            (const __attribute__((address_space(1))) void*)g,
            (__attribute__((address_space(3))) void*)l, 16, 0, 0);
#else
        const unsigned short* g = Av + (long)(id >> 3) * SEQ + c64 * 64 + (id & 7) * 8;
        *reinterpret_cast<uint4*>((char*)buf + swzb(id * 16)) =
            *reinterpret_cast<const uint4*>(g);
#endif
    }
}

// ---------------------------------------------------------------------------
// Fused flash attention (r14 structure, unchanged).
// ---------------------------------------------------------------------------
__global__ __launch_bounds__(256, 2) void flash_attn(
    const unsigned short* __restrict__ Qh,
    const unsigned short* __restrict__ Kh,
    const unsigned short* __restrict__ VhT,
    const float* __restrict__ part,
    unsigned short* __restrict__ Vatt,
    const int* __restrict__ maskc, int bh0, int nbh)
{
    const int tid  = threadIdx.x;
    const int lane = tid & 63;
    const int wave = tid >> 6;
    const int lm   = lane & 15;
    const int qg   = lane >> 4;
    const int kq   = qg * 8;

    const int L = blockIdx.x;
    int z, qt;
    if ((nbh & 7) == 0) {
        int x = L & 7, m = L >> 3;
        int mq = m & 7;
        qt = (mq & 1) ? (7 - (mq >> 1)) : (mq >> 1);   // 0,7,1,6,2,5,3,4
        z  = x + 8 * (m >> 3);
    } else {
        z = L % nbh; qt = L / nbh;
    }
    const int b_l = z >> 2, h = z & 3;
    const int m0  = qt * 64;
    const int wq0 = m0 + wave * 16;
    const long qkbase = (long)b_l * SEQ * HD + (long)h * DM;
    const unsigned short* Aq = Qh + qkbase;
    const unsigned short* Ak = Kh + qkbase;
    const unsigned short* Av = VhT + (long)b_l * SEQ * HD + (long)h * SEQ * DM;
    unsigned short* Ov = Vatt + qkbase;
    const int bglob = (bh0 + z) >> 2;

    __shared__ unsigned short Ks[2 * SEQ * 32];             // 64 KiB dbuf
    __shared__ __align__(16) unsigned short Pw[4][16][40];  // 5 KiB

    f32x4 S[32] = {};
    const int NT = (m0 >> 4) + wave + 1;

    // ---- Phase 1 ----
    stage_k32(Ks, Ak, 0, qt, tid, wave);
    __syncthreads();
    for (int kc = 0; kc < 8; ++kc) {
        unsigned short* cur = (kc & 1) ? (Ks + SEQ * 32) : Ks;
        unsigned short* nxt = (kc & 1) ? Ks : (Ks + SEQ * 32);
        short8 qf = *reinterpret_cast<const short8*>(
            Aq + (long)(wq0 + lm) * HD + kc * 32 + kq);
        if (kc < 7) {
            stage_k32(nxt, Ak, kc + 1, qt, tid, wave);
        } else {
            stage_v64(Ks, Av, 0, tid, wave);
        }
        __builtin_amdgcn_s_setprio(1);
#pragma unroll
        for (int nt = 0; nt < 32; ++nt) {
            if (nt < NT) {
                int row = nt * 16 + lm;
                short8 bf = *reinterpret_cast<const short8*>(
                    (const char*)cur + swzb(row * 64 + qg * 16));
                S[nt] = __builtin_amdgcn_mfma_f32_16x16x32_bf16(qf, bf, S[nt], 0, 0, 0);
            }
        }
        __builtin_amdgcn_s_setprio(0);
        __syncthreads();
    }

    // ---- Softmax ----
    int   qrow[4];
    bool  rowm[4];
    float mx[4], sm[4];
#pragma unroll
    for (int r = 0; r < 4; ++r) {
        int q = wq0 + qg * 4 + r;
        qrow[r] = q;
        rowm[r] = maskc[bglob * SEQ + q] != 0;
        mx[r] = -3.4e38f;
    }
#pragma unroll
    for (int nt = 0; nt < 32; ++nt) {
        int k = nt * 16 + lm;
#pragma unroll
        for (int r = 0; r < 4; ++r) {
            float v = S[nt][r];
            if (k > qrow[r]) v = NEGV;
            S[nt][r] = v;
            mx[r] = fmaxf(mx[r], v);
        }
    }
#pragma unroll
    for (int r = 0; r < 4; ++r) {
#pragma unroll
        for (int off = 8; off >= 1; off >>= 1)
            mx[r] = fmaxf(mx[r], __shfl_xor(mx[r], off));
        sm[r] = 0.f;
    }
    uint32_t pk[32][2];
#pragma unroll
    for (int nt = 0; nt < 32; ++nt) {
        float e0 = fast_exp2(S[nt][0] - mx[0]);
        float e1 = fast_exp2(S[nt][1] - mx[1]);
        float e2 = fast_exp2(S[nt][2] - mx[2]);
        float e3 = fast_exp2(S[nt][3] - mx[3]);
        sm[0] += e0; sm[1] += e1; sm[2] += e2; sm[3] += e3;
        pk[nt][0] = (uint32_t)f2b(e0) | ((uint32_t)f2b(e1) << 16);
        pk[nt][1] = (uint32_t)f2b(e2) | ((uint32_t)f2b(e3) << 16);
    }
#pragma unroll
    for (int r = 0; r < 4; ++r) {
#pragma unroll
        for (int off = 8; off >= 1; off >>= 1)
            sm[r] += __shfl_xor(sm[r], off);
        sm[r] = 1.0f / sm[r];
    }

    // ---- Phase 2 ----
    unsigned short* Vb0 = Ks;
    unsigned short* Vb1 = Ks + 16384;
    const int NC = qt + 1;
    f32x4 O[16] = {};
#pragma unroll
    for (int c64 = 0; c64 < 8; ++c64) {
        if (c64 < NC) {
            unsigned short* Vcur = (c64 & 1) ? Vb1 : Vb0;
            __syncthreads();
            if (c64 + 1 < NC) {
                unsigned short* Vnext = (c64 & 1) ? Vb0 : Vb1;
                stage_v64(Vnext, Av, c64 + 1, tid, wave);
            }
#pragma unroll
            for (int t = 0; t < 2; ++t) {
#pragma unroll
                for (int tt = 0; tt < 2; ++tt) {
                    int nt = c64 * 4 + t * 2 + tt;
#pragma unroll
                    for (int r = 0; r < 4; ++r)
                        Pw[wave][qg * 4 + r][tt * 16 + lm] =
                            (unsigned short)(pk[nt][r >> 1] >> ((r & 1) * 16));
                }
                short8 pf = *reinterpret_cast<const short8*>(&Pw[wave][lm][kq]);
                __builtin_amdgcn_s_setprio(1);
#pragma unroll
                for (int nt2 = 0; nt2 < 16; ++nt2) {
                    int row = nt2 * 16 + lm;
                    short8 vf = *reinterpret_cast<const short8*>(
                        (const char*)Vcur + swzb(row * 128 + t * 64 + qg * 16));
                    O[nt2] = __builtin_amdgcn_mfma_f32_16x16x32_bf16(pf, vf, O[nt2], 0, 0, 0);
                }
                __builtin_amdgcn_s_setprio(0);
            }
        }
    }

    // ---- epilogue ----
    const float* pb = part + (long)(b_l * 8) * HD + h * DM + lm;
    float vmf[16];
#pragma unroll
    for (int nt2 = 0; nt2 < 16; ++nt2) {
        float s = 0.f;
#pragma unroll
        for (int seg = 0; seg < 8; ++seg)
            s += pb[(long)seg * HD + nt2 * 16];
        vmf[nt2] = s * (1.0f / SEQ);
    }
#pragma unroll
    for (int nt2 = 0; nt2 < 16; ++nt2) {
#pragma unroll
        for (int r = 0; r < 4; ++r) {
            int l = wq0 + qg * 4 + r;
            float val = rowm[r] ? vmf[nt2] : O[nt2][r] * sm[r];
            Ov[(long)l * HD + nt2 * 16 + lm] = f2b(val);
        }
    }
}

// ---------------------------------------------------------------------------
// LN1: x = bf16 AttO + fp32 Q + fp32 pe  ->  fp32 Xf AND bf16 Xb
// ---------------------------------------------------------------------------
__global__ __launch_bounds__(256) void ln1_kernel(
    const unsigned short* __restrict__ AttO, const float* __restrict__ Q,
    const float* __restrict__ pe,
    const float* __restrict__ gamma, const float* __restrict__ beta,
    float* __restrict__ outf, unsigned short* __restrict__ outb)
{
    int row  = blockIdx.x * 4 + (threadIdx.x >> 6);
    int lane = threadIdx.x & 63;
    long base = (long)row * DM + lane * 4;
    ushort4 a = *reinterpret_cast<const ushort4*>(AttO + base);
    float4 qv = *reinterpret_cast<const float4*>(Q + base);
    float4 pv = *reinterpret_cast<const float4*>(pe + (base & PE_MASK));
    float x[4] = {b2f(a.x) + qv.x + pv.x, b2f(a.y) + qv.y + pv.y,
                  b2f(a.z) + qv.z + pv.z, b2f(a.w) + qv.w + pv.w};
    float s = x[0] + x[1] + x[2] + x[3];
#pragma unroll
    for (int off = 32; off > 0; off >>= 1) s += __shfl_xor(s, off);
    float mu = s * (1.0f / DM);
    float vs = 0.f;
#pragma unroll
    for (int t = 0; t < 4; ++t) { float d = x[t] - mu; vs += d * d; }
#pragma unroll
    for (int off = 32; off > 0; off >>= 1) vs += __shfl_xor(vs, off);
    float inv = rsqrtf(vs * (1.0f / DM) + 1e-5f);
    int d0 = lane * 4;
    float4 g = *reinterpret_cast<const float4*>(gamma + d0);
    float4 bt = *reinterpret_cast<const float4*>(beta + d0);
    float4 o;
    o.x = (x[0] - mu) * inv * g.x + bt.x;
    o.y = (x[1] - mu) * inv * g.y + bt.y;
    o.z = (x[2] - mu) * inv * g.z + bt.z;
    o.w = (x[3] - mu) * inv * g.w + bt.w;
    *reinterpret_cast<float4*>(outf + base) = o;
    ushort4 ob;
    ob.x = f2b(o.x); ob.y = f2b(o.y); ob.z = f2b(o.z); ob.w = f2b(o.w);
    *reinterpret_cast<ushort4*>(outb + base) = ob;
}

// ---------------------------------------------------------------------------
extern "C" void kernel_launch(void* const* d_in, const int* in_sizes, int n_in,
                              void* d_out, int out_size, void* d_ws, size_t ws_size,
                              hipStream_t stream)
{
    const float* Q  = (const float*)d_in[0];
    const float* Ki = (const float*)d_in[1];
    const float* Vi = (const float*)d_in[2];
    const unsigned char* mask_raw = (const unsigned char*)d_in[3];
    const float* pe = (const float*)d_in[4];
    const float* Wq = (const float*)d_in[5];
    const float* Wk = (const float*)d_in[6];
    const float* Wv = (const float*)d_in[7];
    const float* Wo = (const float*)d_in[8];
    const float* w1 = (const float*)d_in[9];
    const float* b1 = (const float*)d_in[10];
    const float* w2 = (const float*)d_in[11];
    const float* b2 = (const float*)d_in[12];
    const float* gamma = (const float*)d_in[13];
    const float* beta  = (const float*)d_in[14];
    float* out = (float*)d_out;

    const size_t MiB = 1048576;
    char* ws = (char*)d_ws;

    // ---- adaptive chunk size: footprint = 59 + max(5*CB + 32KB*CB, 24) MiB --
    int CB = 1;
    for (int cb = 32; cb >= 1; cb >>= 1) {
        size_t scr_sz = (size_t)(5 * cb) * MiB + (size_t)cb * 32768;
        if (scr_sz < 24 * MiB) scr_sz = 24 * MiB;
        if ((59 * MiB + scr_sz) <= ws_size) { CB = cb; break; }
    }
    const int NCH = NB / CB;

    // ---- fixed low regions ----
    unsigned short* WqT  = (unsigned short*)(ws);                 // 512 KiB each
    unsigned short* WkT  = WqT + 262144;
    unsigned short* WvT  = WkT + 262144;
    unsigned short* WoT  = WvT + 262144;
    unsigned short* w1b  = (unsigned short*)(ws + 2 * MiB);       // 128 KiB
    unsigned short* w2b  = w1b + 65536;                           // 128 KiB
    int*            maskc = (int*)(ws + 2 * MiB + 262144);        // 64 KiB
    unsigned short* Qp   = (unsigned short*)(ws + 3 * MiB);       // 8 MiB bf16
    unsigned short* Kp   = (unsigned short*)(ws + 11 * MiB);      // 8 MiB
    unsigned short* Vp   = (unsigned short*)(ws + 19 * MiB);      // 8 MiB
    unsigned short* AttO = (unsigned short*)(ws + 27 * MiB);      // 8 MiB
    unsigned short* Xb   = (unsigned short*)(ws + 35 * MiB);      // 8 MiB
    float*          Xf   = (float*)(ws + 43 * MiB);               // 16 MiB
    char*           scr  = ws + 59 * MiB;
    // chunk scratch (CB MiB each)
    unsigned short* Qh   = (unsigned short*)(scr);
    unsigned short* Kh   = (unsigned short*)(scr + (size_t)CB * MiB);
    unsigned short* Vh   = (unsigned short*)(scr + (size_t)2 * CB * MiB);
    unsigned short* VhT  = (unsigned short*)(scr + (size_t)3 * CB * MiB);
    unsigned short* Vatt = (unsigned short*)(scr + (size_t)4 * CB * MiB);
    // vmean partial sums (per chunk; dead at tail-alias time)
    float*          part = (float*)(scr + (size_t)5 * CB * MiB);  // CB*32 KiB
    // tail aliases over scratch (chunk buffers dead by then)
    unsigned short* H1   = (unsigned short*)(scr);                // 8 MiB bf16

    // softmax scale * log2(e), folded into the Q projection (z==0 slab)
    const float SCALE_Q = (float)((1.0 / (16.0 + 1e-6)) * 1.4426950408889634);
    const long CROWS = (long)CB * SEQ;
    const long CBELT = (long)CB * MiB / 2;     // chunk-buffer stride, elements

    // 0. fused prep (1 dispatch)
    prep_all<<<13504, 256, 0, stream>>>(
        mask_raw, maskc, Wq, Wk, Wv, WqT, Wo, WoT,
        w1, w2, w1b, w2b, Q, Ki, Vi, pe, Qp, Kp, Vp);

    // 1. attention in NCH chunks of CB batches
    for (int c = 0; c < NCH; ++c) {
        const long r0   = (long)c * CROWS;
        const int  bh0  = c * CB * NH;
        const int  gy   = (int)(CROWS / 128);
        const int  nbh  = CB * NH;

        // all 3 projections in ONE dispatch (z=0: Q scaled by SCALE_Q, 1:K, 2:V)
        gemm_bt<false, false, true><<<dim3(8, gy, 3), 256, 0, stream>>>(
            Qp + r0 * DM, DM, WqT, DM, Qh, HD, nullptr, SCALE_Q, DM,
            1, 4194304, 0, 0, 262144, 0, 0, CBELT, 0, 0);

        // fused per-head V transpose + vmean partial sums (1 dispatch)
        tv_kernel<<<CB * NH * 128 + CB * 8, 256, 0, stream>>>(
            Vh, VhT, part, CB);

        // fused attention (+ masked-row mean + store, 1 dispatch)
        flash_attn<<<dim3(8 * nbh, 1, 1), 256, 0, stream>>>(
            Qh, Kh, VhT, part, Vatt, maskc, bh0, nbh);

        // output projection for this chunk -> AttO rows [r0, r0+CROWS)
        gemm_bt<false, false, true><<<dim3(2, gy, 1), 256, 0, stream>>>(
            Vatt, HD, WoT, HD, AttO + r0 * DM, DM, nullptr, 1.f, HD,
            1, 0,0,0, 0,0,0, 0,0,0);
    }

    // 2. LN1: X = LN(Q + pe + AttO) -> fp32 Xf + bf16 Xb
    ln1_kernel<<<4096, 256, 0, stream>>>(AttO, Q, pe, gamma, beta, Xf, Xb);

    // 3. FFN1: H1 = relu(Xb @ w1^T + b1) -> bf16
    gemm_bt<true, true, true><<<dim3(2, 128, 1), 256, 0, stream>>>(
        Xb, DM, w1b, DM, H1, DM, b1, 1.f, DM, 1, 0,0,0, 0,0,0, 0,0,0);

    // 4. FFN2 + LN2 fused: out = LN((H1@w2^T + b2) + Xf)
    gemm_ln<false, true, false><<<256, 256, 0, stream>>>(
        H1, DM, w2b, DM, b2, Xf, nullptr, gamma, beta,
        out, nullptr, DM, 0);
}